// Round 4
// baseline (12910.495 us; speedup 1.0000x reference)
//
#include <hip/hip_runtime.h>

#define S_LEN 1024
#define BATCH 64
#define HIDDEN 512
#define NBLK 64            // 32 blocks layer-0 + 32 blocks layer-1
#define COLS_PER_BLK 16

typedef __attribute__((ext_vector_type(8))) short short8;   // 8 bf16 (4 VGPRs) MFMA frag
typedef __attribute__((ext_vector_type(4))) float f32x4;    // MFMA accumulator
typedef __attribute__((ext_vector_type(4))) unsigned int u32x4;

__device__ __forceinline__ unsigned short f2bf(float x) {
  unsigned u = __builtin_bit_cast(unsigned, x);
  u += 0x7fffu + ((u >> 16) & 1u);          // round-to-nearest-even
  return (unsigned short)(u >> 16);
}
__device__ __forceinline__ float bf2f(unsigned short h) {
  unsigned u = ((unsigned)h) << 16;
  return __builtin_bit_cast(float, u);
}

// device-scope write-through 16B store (lands at coherence point; no dirty L2 line)
__device__ __forceinline__ void st16_sc1(void* p, u32x4 v) {
  asm volatile("global_store_dwordx4 %0, %1, off sc1" :: "v"(p), "v"(v) : "memory");
}

// fragment load: two relaxed agent (sc1) 8B atomic loads -> 16B MFMA A-fragment.
// Relaxed atomics are NOT hoisted/sunk by LLVM => source position == issue position;
// we exploit that to software-pipeline (issue quarters 2 ahead of consumption).
__device__ __forceinline__ short8 ld_frag(const unsigned long long* p) {
  union { unsigned long long q[2]; short8 s; } u;
  u.q[0] = __hip_atomic_load(p,     __ATOMIC_RELAXED, __HIP_MEMORY_SCOPE_AGENT);
  u.q[1] = __hip_atomic_load(p + 1, __ATOMIC_RELAXED, __HIP_MEMORY_SCOPE_AGENT);
  return u.s;
}

// h state layout: MFMA-A-fragment packed, [parity][wid][kc][lane][8] bf16 shorts.
#define HOFF(p, w, kc, l) ((((((p) * 4 + (w)) * 16 + (kc)) * 64 + (l))) * 8)

// ws layout: [0,1KB) per-wave arrival flags (uint flags[64 blocks][4 waves]);
// then 4 packed h buffers (h0_hi, h0_lo, h1_hi, h1_lo), each 65536 shorts = 128KB.
__global__ void k_init(unsigned* __restrict__ flags, int* __restrict__ hbufs) {
  int i = blockIdx.x * blockDim.x + threadIdx.x;
  if (i < 256) flags[i] = 0u;
  for (int k = i; k < 131072; k += gridDim.x * blockDim.x) hbufs[k] = 0;
}

__launch_bounds__(256, 1)
__global__ void k_rnn(const int* __restrict__ x, const float* __restrict__ emb,
                      const float* __restrict__ Wih0, const float* __restrict__ b0,
                      const float* __restrict__ Whh0, const float* __restrict__ Wih1,
                      const float* __restrict__ b1, const float* __restrict__ Whh1,
                      float* __restrict__ out, unsigned* __restrict__ flags,
                      short* __restrict__ hbase) {
  // LDS: 4 W-fragment regions (ih_hi, ih_lo, hh_hi, hh_lo), each [16 kc][64 lanes][8]
  __shared__ short wlds[4 * 16 * 64 * 8];                 // 64 KB
  __shared__ __align__(16) short stage[2][4][32][8];      // 4 KB publication staging

  const int tid  = threadIdx.x;
  const int wid  = tid >> 6;
  const int lane = tid & 63;
  const int bx   = blockIdx.x;
  const int layer = bx >> 5;                 // 0 or 1
  const int cg    = bx & 31;
  const int col0  = cg * COLS_PER_BLK;

  const float* Wih  = layer ? Wih1 : Wih0;   // [512][512] row-major (k, col)
  const float* Whh  = layer ? Whh1 : Whh0;
  const float* bias = layer ? b1   : b0;

  // ---- stage W column-slices into LDS as pre-packed MFMA B-fragments (hi/lo bf16) ----
  {
    const int c = col0 + (lane & 15);
    for (int kc = wid; kc < 16; kc += 4) {
      const int k0 = kc * 32 + (lane >> 4) * 8;
      const int basei = (kc * 64 + lane) * 8;
      #pragma unroll
      for (int j = 0; j < 8; ++j) {
        float v = Wih[(size_t)(k0 + j) * HIDDEN + c];
        unsigned short vh = f2bf(v);
        wlds[0 * 8192 + basei + j] = (short)vh;
        wlds[1 * 8192 + basei + j] = (short)f2bf(v - bf2f(vh));
        float w = Whh[(size_t)(k0 + j) * HIDDEN + c];
        unsigned short wh = f2bf(w);
        wlds[2 * 8192 + basei + j] = (short)wh;
        wlds[3 * 8192 + basei + j] = (short)f2bf(w - bf2f(wh));
      }
    }
  }
  __syncthreads();

  short* h0_hi = hbase;                       // packed, 65536 shorts each
  short* h0_lo = hbase + 65536;
  short* h1_hi = hbase + 131072;
  short* h1_lo = hbase + 196608;
  const unsigned long long* h0_hi64 = (const unsigned long long*)h0_hi;
  const unsigned long long* h0_lo64 = (const unsigned long long*)h0_lo;
  const unsigned long long* h1_hi64 = (const unsigned long long*)h1_hi;
  const unsigned long long* h1_lo64 = (const unsigned long long*)h1_lo;
  short* hL_hi = layer ? h1_hi : h0_hi;       // this block's output buffers
  short* hL_lo = layer ? h1_lo : h0_lo;

  const int arow  = wid * 16 + (lane & 15);   // A-fragment row = batch index
  const int kgo   = (lane >> 4) * 8;          // k offset inside a 32-chunk
  const int ccol  = col0 + (lane & 15);       // D col (m89-verified C/D map)
  const int drow0 = wid * 16 + (lane >> 4) * 4; // D row base
  const float bc  = bias[ccol];

  // publication coords: ccol maps to packed (skc, lane-slot, j)
  const int skc   = ccol >> 5;
  const int sub0  = (cg & 1) * 2;                    // block's 32-lane window start /16
  const int slotb = (lane >> 4) * 4 + 16 * ((lane & 15) >> 3);  // + j = local slot
  const int sjj   = lane & 7;

  float* out_seq = out;                                  // [64][1024][512]
  float* hidden  = out + (size_t)BATCH * S_LEN * HIDDEN; // [2][64][512]

  short8 ea_reg[16];
  #define LOAD_EA(t) do {                                                   \
    const int xr_ = x[arow * S_LEN + (t)];                                  \
    const float* erow_ = emb + (size_t)xr_ * HIDDEN;                        \
    _Pragma("unroll")                                                       \
    for (int kc = 0; kc < 16; ++kc) {                                       \
      const float4* ep_ = (const float4*)(erow_ + kc * 32 + kgo);           \
      float4 e0_ = ep_[0], e1_ = ep_[1];                                    \
      short8 ea_;                                                           \
      ea_[0] = (short)f2bf(e0_.x); ea_[1] = (short)f2bf(e0_.y);             \
      ea_[2] = (short)f2bf(e0_.z); ea_[3] = (short)f2bf(e0_.w);             \
      ea_[4] = (short)f2bf(e1_.x); ea_[5] = (short)f2bf(e1_.y);             \
      ea_[6] = (short)f2bf(e1_.z); ea_[7] = (short)f2bf(e1_.w);             \
      ea_reg[kc] = ea_;                                                     \
    } } while (0)

  if (layer == 0) LOAD_EA(0);

  // ---- software-pipeline quarters: issue 4-kc load groups 2 ahead of MFMAs ----
  // Layer 0 streams: ha (h0_hi), la (h0_lo). Layer 1: ah, al (h0), ch, cl (h1).
  #define ISSUE_L0(Qh, Ql, qi) do {                                         \
    _Pragma("unroll")                                                       \
    for (int k2 = 0; k2 < 4; ++k2) {                                        \
      const int hoff_ = HOFF(p, wid, (qi) * 4 + k2, lane) >> 2;             \
      Qh[k2] = ld_frag(h0_hi64 + hoff_);                                    \
      Ql[k2] = ld_frag(h0_lo64 + hoff_);                                    \
    } } while (0)

  #define MFMA_L0(Qh, Ql, qi) do {                                          \
    _Pragma("unroll")                                                       \
    for (int k2 = 0; k2 < 4; ++k2) {                                        \
      const int kc_ = (qi) * 4 + k2;                                        \
      const int fb_ = (kc_ * 64 + lane) * 8;                                \
      short8 wih_h = *(const short8*)&wlds[0 * 8192 + fb_];                 \
      short8 wih_l = *(const short8*)&wlds[1 * 8192 + fb_];                 \
      short8 whh_h = *(const short8*)&wlds[2 * 8192 + fb_];                 \
      short8 whh_l = *(const short8*)&wlds[3 * 8192 + fb_];                 \
      f32x4& ac = (k2 & 1) ? acc1 : acc0;                                   \
      ac = __builtin_amdgcn_mfma_f32_16x16x32_bf16(ea_reg[kc_], wih_h, ac, 0, 0, 0); \
      ac = __builtin_amdgcn_mfma_f32_16x16x32_bf16(ea_reg[kc_], wih_l, ac, 0, 0, 0); \
      ac = __builtin_amdgcn_mfma_f32_16x16x32_bf16(Qh[k2], whh_h, ac, 0, 0, 0); \
      ac = __builtin_amdgcn_mfma_f32_16x16x32_bf16(Qh[k2], whh_l, ac, 0, 0, 0); \
      ac = __builtin_amdgcn_mfma_f32_16x16x32_bf16(Ql[k2], whh_h, ac, 0, 0, 0); \
    } } while (0)

  #define ISSUE_L1(Qah, Qal, Qch, Qcl, qi) do {                             \
    _Pragma("unroll")                                                       \
    for (int k2 = 0; k2 < 4; ++k2) {                                        \
      const int ha_ = HOFF(p,  wid, (qi) * 4 + k2, lane) >> 2;              \
      const int hc_ = HOFF(wp, wid, (qi) * 4 + k2, lane) >> 2;              \
      Qah[k2] = ld_frag(h0_hi64 + ha_);                                     \
      Qal[k2] = ld_frag(h0_lo64 + ha_);                                     \
      Qch[k2] = ld_frag(h1_hi64 + hc_);                                     \
      Qcl[k2] = ld_frag(h1_lo64 + hc_);                                     \
    } } while (0)

  #define MFMA_L1(Qah, Qal, Qch, Qcl, qi) do {                              \
    _Pragma("unroll")                                                       \
    for (int k2 = 0; k2 < 4; ++k2) {                                        \
      const int fb_ = (((qi) * 4 + k2) * 64 + lane) * 8;                    \
      short8 wih_h = *(const short8*)&wlds[0 * 8192 + fb_];                 \
      short8 wih_l = *(const short8*)&wlds[1 * 8192 + fb_];                 \
      short8 whh_h = *(const short8*)&wlds[2 * 8192 + fb_];                 \
      short8 whh_l = *(const short8*)&wlds[3 * 8192 + fb_];                 \
      f32x4& ac = (k2 & 1) ? acc1 : acc0;                                   \
      ac = __builtin_amdgcn_mfma_f32_16x16x32_bf16(Qah[k2], wih_h, ac, 0, 0, 0); \
      ac = __builtin_amdgcn_mfma_f32_16x16x32_bf16(Qah[k2], wih_l, ac, 0, 0, 0); \
      ac = __builtin_amdgcn_mfma_f32_16x16x32_bf16(Qal[k2], wih_h, ac, 0, 0, 0); \
      ac = __builtin_amdgcn_mfma_f32_16x16x32_bf16(Qch[k2], whh_h, ac, 0, 0, 0); \
      ac = __builtin_amdgcn_mfma_f32_16x16x32_bf16(Qch[k2], whh_l, ac, 0, 0, 0); \
      ac = __builtin_amdgcn_mfma_f32_16x16x32_bf16(Qcl[k2], whh_h, ac, 0, 0, 0); \
    } } while (0)

  const unsigned long long* f64 = (const unsigned long long*)flags;

  for (int i = 0; i <= S_LEN; ++i) {
    const int p  = i & 1;
    const int wp = p ^ 1;

    if (layer == 0) {
      if (i < S_LEN) {
        f32x4 acc0 = {bc, bc, bc, bc};
        f32x4 acc1 = {0.f, 0.f, 0.f, 0.f};
        short8 QAh[4], QAl[4], QBh[4], QBl[4];
        ISSUE_L0(QAh, QAl, 0);
        ISSUE_L0(QBh, QBl, 1);
        MFMA_L0(QAh, QAl, 0);
        ISSUE_L0(QAh, QAl, 2);
        MFMA_L0(QBh, QBl, 1);
        ISSUE_L0(QBh, QBl, 3);
        MFMA_L0(QAh, QAl, 2);
        MFMA_L0(QBh, QBl, 3);
        #pragma unroll
        for (int j = 0; j < 4; ++j) {
          const int r = drow0 + j;
          float hv = tanhf(acc0[j] + acc1[j]);
          unsigned short hi = f2bf(hv);
          unsigned short lo = f2bf(hv - bf2f(hi));
          stage[0][wid][slotb + j][sjj] = (short)hi;
          stage[1][wid][slotb + j][sjj] = (short)lo;
          if (i == S_LEN - 1) hidden[r * HIDDEN + ccol] = hv;   // hidden[0]
        }
        // intra-wave publication: LDS transpose -> one coalesced 16B sc1 store/thread
        asm volatile("s_waitcnt lgkmcnt(0)" ::: "memory");
        {
          const int l2 = lane & 31, sel = lane >> 5;
          u32x4 v = *(const u32x4*)&stage[sel][wid][l2][0];
          short* dst = (sel ? hL_lo : hL_hi) +
                       (((wp * 4 + wid) * 16 + skc) * 64 + sub0 * 16 + l2) * 8;
          st16_sc1(dst, v);
        }
        if (i + 1 < S_LEN) LOAD_EA(i + 1);   // prefetch next emb (drains with barrier)
      }
    } else {
      if (i >= 1) {
        f32x4 acc0 = {bc, bc, bc, bc};
        f32x4 acc1 = {0.f, 0.f, 0.f, 0.f};
        short8 QAah[4], QAal[4], QAch[4], QAcl[4];
        short8 QBah[4], QBal[4], QBch[4], QBcl[4];
        ISSUE_L1(QAah, QAal, QAch, QAcl, 0);
        ISSUE_L1(QBah, QBal, QBch, QBcl, 1);
        MFMA_L1(QAah, QAal, QAch, QAcl, 0);
        ISSUE_L1(QAah, QAal, QAch, QAcl, 2);
        MFMA_L1(QBah, QBal, QBch, QBcl, 1);
        ISSUE_L1(QBah, QBal, QBch, QBcl, 3);
        MFMA_L1(QAah, QAal, QAch, QAcl, 2);
        MFMA_L1(QBah, QBal, QBch, QBcl, 3);
        const int t = i - 1;
        #pragma unroll
        for (int j = 0; j < 4; ++j) {
          const int r = drow0 + j;
          float hv = tanhf(acc0[j] + acc1[j]);
          unsigned short hi = f2bf(hv);
          unsigned short lo = f2bf(hv - bf2f(hi));
          stage[0][wid][slotb + j][sjj] = (short)hi;
          stage[1][wid][slotb + j][sjj] = (short)lo;
          out_seq[(size_t)r * S_LEN * HIDDEN + (size_t)t * HIDDEN + ccol] = hv;
          if (i == S_LEN) hidden[32768 + r * HIDDEN + ccol] = hv;  // hidden[1]
        }
        asm volatile("s_waitcnt lgkmcnt(0)" ::: "memory");
        {
          const int l2 = lane & 31, sel = lane >> 5;
          u32x4 v = *(const u32x4*)&stage[sel][wid][l2][0];
          short* dst = (sel ? hL_lo : hL_hi) +
                       (((p * 4 + wid) * 16 + skc) * 64 + sub0 * 16 + l2) * 8;
          st16_sc1(dst, v);
        }
      }
    }

    // device-scope barrier i — per-WAVE tag flags; every wave polls independently
    // (no __syncthreads in the barrier at all; intra-wave LDS staging needs none).
    if (i < S_LEN) {
      asm volatile("s_waitcnt vmcnt(0)" ::: "memory");  // this wave's sc1 stores drained
      if (lane == 0)
        __hip_atomic_store(&flags[bx * 4 + wid], (unsigned)(i + 1),
                           __ATOMIC_RELAXED, __HIP_MEMORY_SCOPE_AGENT);
      // lane l watches block l's 4 wave-flags (two 8B atomic loads of one 16B line)
      for (;;) {
        unsigned long long f01 = __hip_atomic_load(f64 + lane * 2,
                                     __ATOMIC_RELAXED, __HIP_MEMORY_SCOPE_AGENT);
        unsigned long long f23 = __hip_atomic_load(f64 + lane * 2 + 1,
                                     __ATOMIC_RELAXED, __HIP_MEMORY_SCOPE_AGENT);
        unsigned m0 = min((unsigned)f01, (unsigned)(f01 >> 32));
        unsigned m1 = min((unsigned)f23, (unsigned)(f23 >> 32));
        if (__all((int)(min(m0, m1) > (unsigned)i))) break;
        __builtin_amdgcn_s_sleep(1);
      }
      asm volatile("" ::: "memory");                    // no hoisting past the spin
    }
  }
  #undef LOAD_EA
  #undef ISSUE_L0
  #undef MFMA_L0
  #undef ISSUE_L1
  #undef MFMA_L1
}

extern "C" void kernel_launch(void* const* d_in, const int* in_sizes, int n_in,
                              void* d_out, int out_size, void* d_ws, size_t ws_size,
                              hipStream_t stream) {
  const int*   x    = (const int*)d_in[0];
  // d_in[1] = lengths : unused by the reference
  const float* emb  = (const float*)d_in[2];
  const float* Wih0 = (const float*)d_in[3];
  const float* b0   = (const float*)d_in[4];
  const float* Whh0 = (const float*)d_in[5];
  const float* Wih1 = (const float*)d_in[6];
  const float* b1   = (const float*)d_in[7];
  const float* Whh1 = (const float*)d_in[8];
  float* out = (float*)d_out;

  unsigned* flags = (unsigned*)d_ws;
  short*    hbase = (short*)((char*)d_ws + 1024);

  // re-zero flags + initial h-state every call (ws not re-poisoned between replays;
  // kernel-boundary flush of k_init makes zeros visible at the coherence point)
  k_init<<<256, 256, 0, stream>>>(flags, (int*)hbase);
  k_rnn<<<NBLK, 256, 0, stream>>>(x, emb, Wih0, b0, Whh0, Wih1, b1, Whh1, out, flags, hbase);
}